// Round 10
// baseline (401.613 us; speedup 1.0000x reference)
//
#include <hip/hip_runtime.h>
#include <hip/hip_fp16.h>
#include <hip/hip_cooperative_groups.h>

// GCNConv: out[v] = isd[v] * sum_{(u->v)} x[u] * isd[u],  isd = rsqrt(max(outdeg,1))
// N=100000, E=1600000, D=128 fp32.
//
// R1 -> R2: bucketed gather killed the 800MB atomic write storm (866 -> 367us).
// R2 -> R3: dst-range slicing for bucket-store L2 locality (367 -> 343us).
// R3 -> R4 FAILED: scope-relaxed atomics don't escape the coherence point.
// R4 -> R5: atomic-free build (hist -> chunk prefix -> LDS-seeded scatter).
// R5 -> R6: chunk parallelism 16->64: 317us.
// R6 -> R7: byte-packed hist: 304us.
// R7 -> R8: scan ILP + fp16 gather: 253us.
// R8 -> R9 FAILED: bitonic-sorted gather (no FETCH drop, +VALU): 262us.
// R9 -> R10: gather unroll8+nt(bucket,out): gather 82.5us BEST; nt on shared
//            edge streams regressed build (+20us). Lesson: nt only for
//            lines no other block re-reads.
// R10 -> R11: nt-reverts + cvt/hist fusion + novf fold: 251us. Build path
//            ~168us vs ~46us of traffic -- 3.5x over BW bound, split invisible
//            (top-5 all gather).
// R11 -> R12: fuse hist -> scan+cvt -> scatter into ONE cooperative kernel
//            (grid.sync between phases): kills 2-3 dispatch drains, keeps H
//            L2-warm, guarantees cvt overlap, and makes the build path a
//            single VISIBLE dispatch for diagnosis. Sync fallback to the
//            R11 multi-kernel path if coop launch is refused.

namespace cg = cooperative_groups;

#define D_FEAT 128
#define CAP 32
#define NODES_PER_BLOCK 8   // gather: 256 threads, 32 lanes per node
#define SS_NODES 50000      // hist superslice (50KB byte-packed LDS)
#define SS_INTS  12500
#define SC_NODES 25000      // scatter slice (3.2MB bucket window < 4MB L2)
#define SC_INTS   6250
#define PCLAMP   200
#define CVTB     512        // cvt role blocks for fallback fused hist

typedef float f32x4 __attribute__((ext_vector_type(4)));

__device__ __forceinline__ void cvt_range(const f32x4* __restrict__ x4,
                                          ushort4* __restrict__ x16,
                                          int start, int stride, int n4) {
    for (int i = start; i < n4; i += stride) {
        f32x4 v = __builtin_nontemporal_load(&x4[i]);   // read-once stream
        ushort4 h;
        h.x = __half_as_ushort(__float2half_rn(v.x));
        h.y = __half_as_ushort(__float2half_rn(v.y));
        h.z = __half_as_ushort(__float2half_rn(v.z));
        h.w = __half_as_ushort(__float2half_rn(v.w));
        x16[i] = h;                                     // cached: gather re-reads
    }
}

// ---- R12 cooperative build: hist -> scan(+cvt) -> scatter (-> cvt modeB) ----
// grid = 2*nss*nc blocks (>= nsc*nc), 256 threads, 50KB LDS -> 3 blocks/CU.
__global__ void __launch_bounds__(256, 2)
build_mega(const int* __restrict__ src, const int* __restrict__ dst,
           unsigned* __restrict__ H, float* __restrict__ isd,
           int* __restrict__ cnt, int* __restrict__ novf,
           int* __restrict__ bucket, int2* __restrict__ ovf,
           const f32x4* __restrict__ x4, ushort4* __restrict__ x16,
           int n4, int modeA,
           int E, int N, int nss, int nsc, int chunkSz, int nc) {
    cg::grid_group grid = cg::this_grid();
    __shared__ unsigned lds[SS_INTS];
    int bid = blockIdx.x;
    int nb  = gridDim.x;
    int tid = (int)threadIdx.x;

    // ---- phase 1: hist (job = bid) ----
    {
        int ax = bid & 1;                        // 0 = src (deg), 1 = dst (cnt)
        int ss = (bid >> 1) % nss;
        int c  = bid / (2 * nss);
        const int* __restrict__ arr = ax ? dst : src;
        int lo = ss * SS_NODES;
        int span = min(N - lo, SS_NODES);
        for (int i = tid; i < SS_INTS; i += blockDim.x) lds[i] = 0u;
        __syncthreads();

        int beg = c * chunkSz;
        int end = min(E, beg + chunkSz);
        int i = beg + tid * 4;
        for (; i + 3 < end; i += blockDim.x * 4) {
            int4 v = *reinterpret_cast<const int4*>(&arr[i]);
            unsigned o;
            o = (unsigned)(v.x - lo); if (o < (unsigned)span) atomicAdd(&lds[o >> 2], 1u << (8 * (o & 3)));
            o = (unsigned)(v.y - lo); if (o < (unsigned)span) atomicAdd(&lds[o >> 2], 1u << (8 * (o & 3)));
            o = (unsigned)(v.z - lo); if (o < (unsigned)span) atomicAdd(&lds[o >> 2], 1u << (8 * (o & 3)));
            o = (unsigned)(v.w - lo); if (o < (unsigned)span) atomicAdd(&lds[o >> 2], 1u << (8 * (o & 3)));
        }
        if (i < end) {
            for (int k = i; k < end; ++k) {
                unsigned o = (unsigned)(arr[k] - lo);
                if (o < (unsigned)span) atomicAdd(&lds[o >> 2], 1u << (8 * (o & 3)));
            }
        }
        __syncthreads();

        size_t base = ((size_t)(ax * nss + ss) * nc + c) * SS_INTS;
        for (int j = tid; j < SS_INTS; j += blockDim.x) H[base + j] = lds[j];
        if (bid == 0 && tid == 0) *novf = 0;
    }
    grid.sync();

    // ---- phase 2: scan (threads < S) + cvt overlap (mode A, threads >= S) ----
    {
        int total = nss * SS_INTS;
        int S = 2 * total;
        int T = nb * (int)blockDim.x;
        int g = bid * (int)blockDim.x + tid;
        if (g < S) {
            int ax = (g >= total) ? 1 : 0;
            int gg = g - ax * total;
            int ss = gg / SS_INTS;
            int i  = gg - ss * SS_INTS;
            int node0 = ss * SS_NODES + 4 * i;
            size_t base = ((size_t)(ax * nss + ss) * nc) * SS_INTS + i;

            if (ax == 0) {
                int s0 = 0, s1 = 0, s2 = 0, s3 = 0;
                for (int c = 0; c < nc; c += 8) {
                    unsigned w[8];
                    #pragma unroll
                    for (int u = 0; u < 8; ++u) w[u] = H[base + (size_t)(c + u) * SS_INTS];
                    #pragma unroll
                    for (int u = 0; u < 8; ++u) {
                        s0 += w[u] & 255; s1 += (w[u] >> 8) & 255;
                        s2 += (w[u] >> 16) & 255; s3 += w[u] >> 24;
                    }
                }
                if (node0 + 0 < N) isd[node0 + 0] = rsqrtf(fmaxf((float)s0, 1.0f));
                if (node0 + 1 < N) isd[node0 + 1] = rsqrtf(fmaxf((float)s1, 1.0f));
                if (node0 + 2 < N) isd[node0 + 2] = rsqrtf(fmaxf((float)s2, 1.0f));
                if (node0 + 3 < N) isd[node0 + 3] = rsqrtf(fmaxf((float)s3, 1.0f));
            } else {
                int r0 = 0, r1 = 0, r2 = 0, r3 = 0;
                for (int c = 0; c < nc; c += 8) {
                    unsigned w[8];
                    #pragma unroll
                    for (int u = 0; u < 8; ++u) w[u] = H[base + (size_t)(c + u) * SS_INTS];
                    #pragma unroll
                    for (int u = 0; u < 8; ++u) {
                        unsigned p = (unsigned)min(r0, PCLAMP) | ((unsigned)min(r1, PCLAMP) << 8) |
                                     ((unsigned)min(r2, PCLAMP) << 16) | ((unsigned)min(r3, PCLAMP) << 24);
                        H[base + (size_t)(c + u) * SS_INTS] = p;
                        r0 += w[u] & 255; r1 += (w[u] >> 8) & 255;
                        r2 += (w[u] >> 16) & 255; r3 += w[u] >> 24;
                    }
                }
                if (node0 + 0 < N) cnt[node0 + 0] = r0;
                if (node0 + 1 < N) cnt[node0 + 1] = r1;
                if (node0 + 2 < N) cnt[node0 + 2] = r2;
                if (node0 + 3 < N) cnt[node0 + 3] = r3;
            }
        } else if (modeA) {
            cvt_range(x4, x16, g - S, T - S, n4);
        }
    }
    grid.sync();

    // ---- phase 3: scatter (job = bid; guard for grid > nsc*nc) ----
    {
        int s = bid % nsc;                       // XCD-pinning heuristic
        int c = bid / nsc;
        if (c < nc) {
            int lo = s * SC_NODES;
            int span = min(N - lo, SC_NODES);
            int ss = s >> 1;                     // SC = SS/2
            size_t base = ((size_t)(nss + ss) * nc + c) * SS_INTS + (size_t)(s & 1) * SC_INTS;
            for (int i = tid; i < SC_INTS; i += blockDim.x) lds[i] = H[base + i];
            __syncthreads();

            int beg = c * chunkSz;
            int end = min(E, beg + chunkSz);
            int i = beg + tid * 4;
            for (; i + 3 < end; i += blockDim.x * 4) {
                int4 dv = *reinterpret_cast<const int4*>(&dst[i]);
                int4 sv = *reinterpret_cast<const int4*>(&src[i]);
                #pragma unroll
                for (int k = 0; k < 4; ++k) {
                    int d  = (&dv.x)[k];
                    int sx = (&sv.x)[k];
                    unsigned o = (unsigned)(d - lo);
                    if (o < (unsigned)span) {
                        int sh = 8 * (o & 3);
                        unsigned old = atomicAdd(&lds[o >> 2], 1u << sh);
                        int slot = (old >> sh) & 255;
                        if (slot < CAP) {
                            bucket[d * CAP + slot] = sx;
                        } else {
                            int ov = atomicAdd(novf, 1);
                            ovf[ov] = make_int2(sx, d);
                        }
                    }
                }
            }
            if (i < end) {
                for (int k = i; k < end; ++k) {
                    int d  = dst[k];
                    int sx = src[k];
                    unsigned o = (unsigned)(d - lo);
                    if (o < (unsigned)span) {
                        int sh = 8 * (o & 3);
                        unsigned old = atomicAdd(&lds[o >> 2], 1u << sh);
                        int slot = (old >> sh) & 255;
                        if (slot < CAP) {
                            bucket[d * CAP + slot] = sx;
                        } else {
                            int ov = atomicAdd(novf, 1);
                            ovf[ov] = make_int2(sx, d);
                        }
                    }
                }
            }
        }
    }

    // ---- phase 4 (mode B only): cvt after scatter (x16 unions H) ----
    if (!modeA) {
        grid.sync();
        int T = nb * (int)blockDim.x;
        int g = bid * (int)blockDim.x + tid;
        cvt_range(x4, x16, g, T, n4);
    }
}

// ---- fallback standalone build kernels (non-cooperative path) ----

__global__ void hist_kernel(const int* __restrict__ src, const int* __restrict__ dst,
                            unsigned* __restrict__ H, int E, int N,
                            int nss, int chunkSz, int nc, int histBlocks,
                            const f32x4* __restrict__ x4,
                            ushort4* __restrict__ x16, int n4) {
    int bid = blockIdx.x;
    if (bid >= histBlocks) {                     // cvt role (mode A only)
        cvt_range(x4, x16, (bid - histBlocks) * (int)blockDim.x + (int)threadIdx.x,
                  CVTB * (int)blockDim.x, n4);
        return;
    }
    int ax = bid & 1;
    int ss = (bid >> 1) % nss;
    int c  = bid / (2 * nss);
    const int* __restrict__ arr = ax ? dst : src;

    __shared__ unsigned hp[SS_INTS];
    int lo = ss * SS_NODES;
    int span = min(N - lo, SS_NODES);
    for (int i = threadIdx.x; i < SS_INTS; i += blockDim.x) hp[i] = 0u;
    __syncthreads();

    int beg = c * chunkSz;
    int end = min(E, beg + chunkSz);
    int i = beg + (int)threadIdx.x * 4;
    for (; i + 3 < end; i += blockDim.x * 4) {
        int4 v = *reinterpret_cast<const int4*>(&arr[i]);
        unsigned o;
        o = (unsigned)(v.x - lo); if (o < (unsigned)span) atomicAdd(&hp[o >> 2], 1u << (8 * (o & 3)));
        o = (unsigned)(v.y - lo); if (o < (unsigned)span) atomicAdd(&hp[o >> 2], 1u << (8 * (o & 3)));
        o = (unsigned)(v.z - lo); if (o < (unsigned)span) atomicAdd(&hp[o >> 2], 1u << (8 * (o & 3)));
        o = (unsigned)(v.w - lo); if (o < (unsigned)span) atomicAdd(&hp[o >> 2], 1u << (8 * (o & 3)));
    }
    if (i < end) {
        for (int k = i; k < end; ++k) {
            unsigned o = (unsigned)(arr[k] - lo);
            if (o < (unsigned)span) atomicAdd(&hp[o >> 2], 1u << (8 * (o & 3)));
        }
    }
    __syncthreads();

    size_t base = ((size_t)(ax * nss + ss) * nc + c) * SS_INTS;
    for (int j = threadIdx.x; j < SS_INTS; j += blockDim.x) H[base + j] = hp[j];
}

__global__ void scan_kernel(unsigned* __restrict__ H, float* __restrict__ isd,
                            int* __restrict__ cnt, int* __restrict__ novf,
                            int N, int nss, int nc) {
    int total = nss * SS_INTS;
    int g = blockIdx.x * blockDim.x + threadIdx.x;
    if (g == 0) *novf = 0;
    if (g >= 2 * total) return;
    int ax = (g >= total) ? 1 : 0;
    int gg = g - ax * total;
    int ss = gg / SS_INTS;
    int i  = gg - ss * SS_INTS;
    int node0 = ss * SS_NODES + 4 * i;
    size_t base = ((size_t)(ax * nss + ss) * nc) * SS_INTS + i;

    if (ax == 0) {
        int s0 = 0, s1 = 0, s2 = 0, s3 = 0;
        for (int c = 0; c < nc; c += 8) {
            unsigned w[8];
            #pragma unroll
            for (int u = 0; u < 8; ++u) w[u] = H[base + (size_t)(c + u) * SS_INTS];
            #pragma unroll
            for (int u = 0; u < 8; ++u) {
                s0 += w[u] & 255; s1 += (w[u] >> 8) & 255;
                s2 += (w[u] >> 16) & 255; s3 += w[u] >> 24;
            }
        }
        if (node0 + 0 < N) isd[node0 + 0] = rsqrtf(fmaxf((float)s0, 1.0f));
        if (node0 + 1 < N) isd[node0 + 1] = rsqrtf(fmaxf((float)s1, 1.0f));
        if (node0 + 2 < N) isd[node0 + 2] = rsqrtf(fmaxf((float)s2, 1.0f));
        if (node0 + 3 < N) isd[node0 + 3] = rsqrtf(fmaxf((float)s3, 1.0f));
    } else {
        int r0 = 0, r1 = 0, r2 = 0, r3 = 0;
        for (int c = 0; c < nc; c += 8) {
            unsigned w[8];
            #pragma unroll
            for (int u = 0; u < 8; ++u) w[u] = H[base + (size_t)(c + u) * SS_INTS];
            #pragma unroll
            for (int u = 0; u < 8; ++u) {
                unsigned p = (unsigned)min(r0, PCLAMP) | ((unsigned)min(r1, PCLAMP) << 8) |
                             ((unsigned)min(r2, PCLAMP) << 16) | ((unsigned)min(r3, PCLAMP) << 24);
                H[base + (size_t)(c + u) * SS_INTS] = p;
                r0 += w[u] & 255; r1 += (w[u] >> 8) & 255;
                r2 += (w[u] >> 16) & 255; r3 += w[u] >> 24;
            }
        }
        if (node0 + 0 < N) cnt[node0 + 0] = r0;
        if (node0 + 1 < N) cnt[node0 + 1] = r1;
        if (node0 + 2 < N) cnt[node0 + 2] = r2;
        if (node0 + 3 < N) cnt[node0 + 3] = r3;
    }
}

__global__ void scatter_kernel(const int* __restrict__ src, const int* __restrict__ dst,
                               const unsigned* __restrict__ H,
                               int* __restrict__ bucket, int2* __restrict__ ovf,
                               int* __restrict__ novf, int E, int N,
                               int nss, int nsc, int chunkSz, int nc) {
    int bid = blockIdx.x;
    int s = bid % nsc;
    int c = bid / nsc;

    __shared__ unsigned lcp[SC_INTS];
    int lo = s * SC_NODES;
    int span = min(N - lo, SC_NODES);
    int ss = s >> 1;
    size_t base = ((size_t)(nss + ss) * nc + c) * SS_INTS + (size_t)(s & 1) * SC_INTS;
    for (int i = threadIdx.x; i < SC_INTS; i += blockDim.x) lcp[i] = H[base + i];
    __syncthreads();

    int beg = c * chunkSz;
    int end = min(E, beg + chunkSz);
    int i = beg + (int)threadIdx.x * 4;
    for (; i + 3 < end; i += blockDim.x * 4) {
        int4 dv = *reinterpret_cast<const int4*>(&dst[i]);
        int4 sv = *reinterpret_cast<const int4*>(&src[i]);
        #pragma unroll
        for (int k = 0; k < 4; ++k) {
            int d  = (&dv.x)[k];
            int sx = (&sv.x)[k];
            unsigned o = (unsigned)(d - lo);
            if (o < (unsigned)span) {
                int sh = 8 * (o & 3);
                unsigned old = atomicAdd(&lcp[o >> 2], 1u << sh);
                int slot = (old >> sh) & 255;
                if (slot < CAP) {
                    bucket[d * CAP + slot] = sx;
                } else {
                    int ov = atomicAdd(novf, 1);
                    ovf[ov] = make_int2(sx, d);
                }
            }
        }
    }
    if (i < end) {
        for (int k = i; k < end; ++k) {
            int d  = dst[k];
            int sx = src[k];
            unsigned o = (unsigned)(d - lo);
            if (o < (unsigned)span) {
                int sh = 8 * (o & 3);
                unsigned old = atomicAdd(&lcp[o >> 2], 1u << sh);
                int slot = (old >> sh) & 255;
                if (slot < CAP) {
                    bucket[d * CAP + slot] = sx;
                } else {
                    int ov = atomicAdd(novf, 1);
                    ovf[ov] = make_int2(sx, d);
                }
            }
        }
    }
}

__global__ void cvt_kernel(const f32x4* __restrict__ x4,
                           ushort4* __restrict__ x16, int n4) {
    int i = blockIdx.x * blockDim.x + threadIdx.x;
    if (i < n4) cvt_range(x4, x16, i, n4, n4);   // single element
}

// 8 nodes per 256-thread block; 32 lanes per node, 4 halves (8B) per lane.
__global__ void gather_kernel(const ushort4* __restrict__ x16,
                              const int* __restrict__ cnt,
                              const int* __restrict__ bucket,
                              const float* __restrict__ isd,
                              f32x4* __restrict__ out4, int N) {
    __shared__ int   sh_idx[NODES_PER_BLOCK * CAP];
    __shared__ float sh_w[NODES_PER_BLOCK * CAP];
    int t = threadIdx.x;
    int node_slot = t >> 5;
    int lane = t & 31;
    int d = blockIdx.x * NODES_PER_BLOCK + node_slot;

    int c = 0;
    if (d < N) {
        c = min(cnt[d], CAP);
        if (lane < c) {
            int s = __builtin_nontemporal_load(&bucket[d * CAP + lane]);  // read-once
            sh_idx[node_slot * CAP + lane] = s;
            sh_w[node_slot * CAP + lane] = isd[s];
        }
    }
    __syncthreads();
    if (d >= N) return;

    f32x4 acc = {0.f, 0.f, 0.f, 0.f};
    #pragma unroll 8
    for (int k = 0; k < c; ++k) {
        int s   = sh_idx[node_slot * CAP + k];   // broadcast LDS read
        float w = sh_w[node_slot * CAP + k];
        ushort4 v = x16[s * 32 + lane];          // 256B coalesced half-row gather
        acc.x += __half2float(__ushort_as_half(v.x)) * w;
        acc.y += __half2float(__ushort_as_half(v.y)) * w;
        acc.z += __half2float(__ushort_as_half(v.z)) * w;
        acc.w += __half2float(__ushort_as_half(v.w)) * w;
    }
    float wd = isd[d];
    acc.x *= wd; acc.y *= wd; acc.z *= wd; acc.w *= wd;
    __builtin_nontemporal_store(acc, &out4[d * 32 + lane]);  // write-once
}

__global__ void overflow_kernel(const float* __restrict__ x,
                                const float* __restrict__ isd,
                                const int2* __restrict__ ovf,
                                const int* __restrict__ novf,
                                float* __restrict__ out) {
    int n = *novf;
    for (int e = blockIdx.x; e < n; e += gridDim.x) {
        int2 sd = ovf[e];
        float coef = isd[sd.x] * isd[sd.y];
        atomicAdd(&out[sd.y * D_FEAT + threadIdx.x],
                  x[sd.x * D_FEAT + threadIdx.x] * coef);
    }
}

// fp32 gather for tier-2
__global__ void gather32_kernel(const float4* __restrict__ x4,
                                const int* __restrict__ cnt,
                                const int* __restrict__ bucket,
                                const float* __restrict__ isd,
                                float4* __restrict__ out4, int N) {
    __shared__ int   sh_idx[NODES_PER_BLOCK * CAP];
    __shared__ float sh_w[NODES_PER_BLOCK * CAP];
    int t = threadIdx.x;
    int node_slot = t >> 5;
    int lane = t & 31;
    int d = blockIdx.x * NODES_PER_BLOCK + node_slot;

    int c = 0;
    if (d < N) {
        c = min(cnt[d], CAP);
        if (lane < c) {
            int s = bucket[d * CAP + lane];
            sh_idx[node_slot * CAP + lane] = s;
            sh_w[node_slot * CAP + lane] = isd[s];
        }
    }
    __syncthreads();
    if (d >= N) return;

    float4 acc = {0.f, 0.f, 0.f, 0.f};
    #pragma unroll 4
    for (int k = 0; k < c; ++k) {
        int s   = sh_idx[node_slot * CAP + k];
        float w = sh_w[node_slot * CAP + k];
        float4 v = x4[s * 32 + lane];
        acc.x += v.x * w; acc.y += v.y * w;
        acc.z += v.z * w; acc.w += v.w * w;
    }
    float wd = isd[d];
    acc.x *= wd; acc.y *= wd; acc.z *= wd; acc.w *= wd;
    out4[d * 32 + lane] = acc;
}

// ---- tier-2 (ws too small for scratch): atomic build ----
#define NSLICES_T2 8
#define BPS 512

__global__ void build_kernel(const int* __restrict__ src, const int* __restrict__ dst,
                             int* __restrict__ deg, int* __restrict__ cnt,
                             int* __restrict__ bucket, int2* __restrict__ ovf,
                             int* __restrict__ novf, int E, int sliceSz) {
    int slice = blockIdx.x & (NSLICES_T2 - 1);
    int chunk = blockIdx.x >> 3;
    int lo = slice * sliceSz;
    int hi = lo + sliceSz;
    int chunkSz = (E + BPS - 1) / BPS;
    int beg = chunk * chunkSz;
    int end = min(E, beg + chunkSz);

    for (int i = beg + (int)threadIdx.x; i < end; i += blockDim.x) {
        int s = src[i];
        int d = dst[i];
        if (d >= lo && d < hi) {
            int slot = atomicAdd(&cnt[d], 1);
            if (slot < CAP) {
                bucket[d * CAP + slot] = s;
            } else {
                int o = atomicAdd(novf, 1);
                ovf[o] = make_int2(s, d);
            }
        }
        if (s >= lo && s < hi) {
            atomicAdd(&deg[s], 1);
        }
    }
}

__global__ void isd_kernel(const int* __restrict__ deg, float* __restrict__ isd, int N) {
    int i = blockIdx.x * blockDim.x + threadIdx.x;
    if (i < N) isd[i] = rsqrtf(fmaxf((float)deg[i], 1.0f));
}

// ---- tier-3 fallback (ws tiny): round-1 atomic scatter ----
__global__ void fb_degree_kernel(const int* __restrict__ src,
                                 float* __restrict__ deg, int E) {
    int i = blockIdx.x * blockDim.x + threadIdx.x;
    if (i < E) atomicAdd(&deg[src[i]], 1.0f);
}
__global__ void fb_inv_sqrt_kernel(float* __restrict__ deg, int N) {
    int i = blockIdx.x * blockDim.x + threadIdx.x;
    if (i < N) deg[i] = rsqrtf(fmaxf(deg[i], 1.0f));
}
__global__ void fb_scatter_kernel(const float* __restrict__ x,
                                  const int* __restrict__ src,
                                  const int* __restrict__ dst,
                                  const float* __restrict__ isd,
                                  float* __restrict__ out, int E) {
    int e = blockIdx.x;
    if (e >= E) return;
    int f = threadIdx.x;
    int s = src[e], d = dst[e];
    float coef = isd[s] * isd[d];
    atomicAdd(&out[(long)d * D_FEAT + f], x[(long)s * D_FEAT + f] * coef);
}

extern "C" void kernel_launch(void* const* d_in, const int* in_sizes, int n_in,
                              void* d_out, int out_size, void* d_ws, size_t ws_size,
                              hipStream_t stream) {
    const float* x   = (const float*)d_in[0];
    const int*   src = (const int*)d_in[1];
    const int*   dst = (const int*)d_in[2];
    float* out = (float*)d_out;

    int N = in_sizes[0] / D_FEAT;   // 100000
    int E = in_sizes[1];            // 1600000

    int nss = (N + SS_NODES - 1) / SS_NODES;    // 2
    int nsc = (N + SC_NODES - 1) / SC_NODES;    // 4

    size_t x16Sz = (size_t)N * D_FEAT * 2;      // 25.6 MB fp16 copy of x
    int n4 = N * (D_FEAT / 4);

    // pick largest chunk count; prefer layout A (separate x16)
    int nc = 0, modeA = 0;
    size_t off_cnt = 0, off_isd = 0, off_misc = 0, off_bucket = 0,
           off_H = 0, off_x16 = 0, off_ovf = 0;
    for (int tryNc = 128; tryNc >= 16 && nc == 0; tryNc >>= 1) {
        size_t hSz = (size_t)2 * nss * tryNc * SS_INTS * 4;
        size_t cA  = 0;
        off_cnt    = cA;                         cA += (size_t)N * 4;
        off_isd    = cA;                         cA += (size_t)N * 4;
        off_misc   = cA;                         cA += 64;       // novf
        off_bucket = cA;                         cA += (size_t)N * CAP * 4;
        off_H      = cA;
        size_t a_x16 = off_H + hSz;
        size_t a_ovf = a_x16 + x16Sz;
        size_t a_need = a_ovf + (size_t)E * 8;
        if (ws_size >= a_need) {
            nc = tryNc; modeA = 1; off_x16 = a_x16; off_ovf = a_ovf;
            break;
        }
        size_t uSz = hSz > x16Sz ? hSz : x16Sz;
        size_t b_ovf = off_H + uSz;
        size_t b_need = b_ovf + (size_t)E * 8;
        if (ws_size >= b_need) {
            nc = tryNc; modeA = 0; off_x16 = off_H; off_ovf = b_ovf;
            break;
        }
    }

    if (nc > 0) {
        char* ws = (char*)d_ws;
        int*      cnt    = (int*)(ws + off_cnt);
        float*    isd    = (float*)(ws + off_isd);
        int*      novf   = (int*)(ws + off_misc);
        int*      bucket = (int*)(ws + off_bucket);
        unsigned* H      = (unsigned*)(ws + off_H);
        ushort4*  x16    = (ushort4*)(ws + off_x16);
        int2*     ovf    = (int2*)(ws + off_ovf);

        int chunkSz = (((E + nc - 1) / nc) + 3) & ~3;   // 4-aligned
        int nb = 2 * nss * nc;                          // coop grid (>= nsc*nc)

        const f32x4* x4 = (const f32x4*)x;
        const int* src_ = src;
        const int* dst_ = dst;
        void* args[] = { (void*)&src_, (void*)&dst_, (void*)&H, (void*)&isd,
                         (void*)&cnt, (void*)&novf, (void*)&bucket, (void*)&ovf,
                         (void*)&x4, (void*)&x16, (void*)&n4, (void*)&modeA,
                         (void*)&E, (void*)&N, (void*)&nss, (void*)&nsc,
                         (void*)&chunkSz, (void*)&nc };
        hipError_t cerr = hipLaunchCooperativeKernel(
            reinterpret_cast<void*>(build_mega), dim3(nb), dim3(256),
            args, 0, stream);

        if (cerr != hipSuccess) {
            // fallback: R11 multi-kernel build path
            int histBlocks = nb;
            if (modeA) {
                hist_kernel<<<histBlocks + CVTB, 256, 0, stream>>>(
                    src, dst, H, E, N, nss, chunkSz, nc, histBlocks,
                    (const f32x4*)x, x16, n4);
            } else {
                hist_kernel<<<histBlocks, 256, 0, stream>>>(
                    src, dst, H, E, N, nss, chunkSz, nc, histBlocks,
                    (const f32x4*)x, x16, 0);
            }
            scan_kernel<<<(2 * nss * SS_INTS + 255) / 256, 256, 0, stream>>>(
                H, isd, cnt, novf, N, nss, nc);
            scatter_kernel<<<nsc * nc, 256, 0, stream>>>(
                src, dst, H, bucket, ovf, novf, E, N, nss, nsc, chunkSz, nc);
            if (!modeA) {
                cvt_kernel<<<(n4 + 255) / 256, 256, 0, stream>>>(
                    (const f32x4*)x, x16, n4);
            }
        }

        gather_kernel<<<(N + NODES_PER_BLOCK - 1) / NODES_PER_BLOCK, 256, 0, stream>>>(
            x16, cnt, bucket, isd, (f32x4*)out, N);
        overflow_kernel<<<64, D_FEAT, 0, stream>>>(x, isd, ovf, novf, out);
        return;
    }

    // tier-2: atomic build (needs ~26.8MB)
    size_t t2_deg    = 0;
    size_t t2_cnt    = t2_deg + (size_t)N * 4;
    size_t t2_isd    = t2_cnt + (size_t)N * 4;
    size_t t2_novf   = t2_isd + (size_t)N * 4;
    size_t t2_bucket = t2_novf + 16;
    size_t t2_ovf    = t2_bucket + (size_t)N * CAP * 4;
    size_t t2_needed = t2_ovf + (size_t)E * 8;

    if (ws_size >= t2_needed) {
        char* ws = (char*)d_ws;
        int*   deg    = (int*)(ws + t2_deg);
        int*   cnt    = (int*)(ws + t2_cnt);
        float* isd    = (float*)(ws + t2_isd);
        int*   novf   = (int*)(ws + t2_novf);
        int*   bucket = (int*)(ws + t2_bucket);
        int2*  ovf    = (int2*)(ws + t2_ovf);

        hipMemsetAsync(ws, 0, t2_novf + 16, stream);
        int sl = (N + NSLICES_T2 - 1) / NSLICES_T2;
        build_kernel<<<NSLICES_T2 * BPS, 256, 0, stream>>>(src, dst, deg, cnt,
                                                           bucket, ovf, novf, E, sl);
        isd_kernel<<<(N + 255) / 256, 256, 0, stream>>>(deg, isd, N);
        gather32_kernel<<<(N + NODES_PER_BLOCK - 1) / NODES_PER_BLOCK, 256, 0, stream>>>(
            (const float4*)x, cnt, bucket, isd, (float4*)out, N);
        overflow_kernel<<<64, D_FEAT, 0, stream>>>(x, isd, ovf, novf, out);
        return;
    }

    // tier-3 naive
    float* deg = (float*)d_ws;
    hipMemsetAsync(deg, 0, (size_t)N * sizeof(float), stream);
    hipMemsetAsync(out, 0, (size_t)out_size * sizeof(float), stream);
    fb_degree_kernel<<<(E + 255) / 256, 256, 0, stream>>>(src, deg, E);
    fb_inv_sqrt_kernel<<<(N + 255) / 256, 256, 0, stream>>>(deg, N);
    fb_scatter_kernel<<<E, D_FEAT, 0, stream>>>(x, src, dst, deg, out, E);
}

// Round 11
// 251.543 us; speedup vs baseline: 1.5966x; 1.5966x over previous
//
#include <hip/hip_runtime.h>
#include <hip/hip_fp16.h>

// GCNConv: out[v] = isd[v] * sum_{(u->v)} x[u] * isd[u],  isd = rsqrt(max(outdeg,1))
// N=100000, E=1600000, D=128 fp32.
//
// R1 -> R2: bucketed gather killed the 800MB atomic write storm (866 -> 367us).
// R2 -> R3: dst-range slicing for bucket-store L2 locality (367 -> 343us).
// R3 -> R4 FAILED: scope-relaxed atomics don't escape the coherence point.
// R4 -> R5: atomic-free build (hist -> chunk prefix -> LDS-seeded scatter).
// R5 -> R6: chunk parallelism 16->64: 317us.
// R6 -> R7: byte-packed hist: 304us.
// R7 -> R8: scan ILP + fp16 gather: 253us.
// R8 -> R9 FAILED: bitonic-sorted gather (no FETCH drop, +VALU): 262us.
// R9 -> R10: gather unroll8 + nt(bucket,out): gather 82.5us (floor); nt on
//            SHARED edge streams regressed build. Lesson: nt only for lines
//            no other block re-reads.
// R10 -> R11: nt-reverts + cvt/hist fusion + novf fold: 251us.
// R11 -> R12 FAILED (402us) but diagnostic GOLD: fused build showed 23%
//            occupancy, VALU 3.2%, HBM 12% -- build path is LATENCY-bound at
//            2-3 blocks/CU because the 50KB LDS histogram caps residency.
//            Traffic (~200MB) only accounts for ~50us of the ~168us.
// R12 -> R13: revert to R11 multi-kernel; histogram slice 50KB -> 12.5KB
//            (12500 nodes byte-packed): 8 blocks/CU = 100% occupancy for
//            hist+scatter. nss=nsc=8; slice%8 matches the 8-XCD round-robin
//            (1.6MB bucket window per XCD L2). Edge re-scan 8x is L3-resident
//            (+15us BW) -- cheap vs the latency win.

#define D_FEAT 128
#define CAP 32
#define NODES_PER_BLOCK 8   // gather: 256 threads, 32 lanes per node
#define SS_NODES 12500      // hist slice: 12.5KB byte-packed LDS -> 8 blocks/CU
#define SS_INTS   3125
#define SC_NODES 12500      // scatter slice == hist slice (1.6MB bucket window)
#define SC_INTS   3125
#define PCLAMP   200
#define CVTB     512        // cvt role blocks fused into hist launch (mode A)

typedef float f32x4 __attribute__((ext_vector_type(4)));

__device__ __forceinline__ void cvt_range(const f32x4* __restrict__ x4,
                                          ushort4* __restrict__ x16,
                                          int start, int stride, int n4) {
    for (int i = start; i < n4; i += stride) {
        f32x4 v = __builtin_nontemporal_load(&x4[i]);   // read-once stream
        ushort4 h;
        h.x = __half_as_ushort(__float2half_rn(v.x));
        h.y = __half_as_ushort(__float2half_rn(v.y));
        h.z = __half_as_ushort(__float2half_rn(v.z));
        h.w = __half_as_ushort(__float2half_rn(v.w));
        x16[i] = h;                                     // cached: gather re-reads
    }
}

// ---- atomic-free build pipeline (byte-packed, 12.5KB slices) ----

// Blocks [0, histBlocks): per-(axis,slice,chunk) LDS histogram.
// Blocks [histBlocks, +CVTB): grid-stride fp32->fp16 convert (mode A overlap).
__global__ void hist_kernel(const int* __restrict__ src, const int* __restrict__ dst,
                            unsigned* __restrict__ H, int E, int N,
                            int nss, int chunkSz, int nc, int histBlocks,
                            const f32x4* __restrict__ x4,
                            ushort4* __restrict__ x16, int n4) {
    int bid = blockIdx.x;
    if (bid >= histBlocks) {                     // cvt role (mode A only)
        cvt_range(x4, x16, (bid - histBlocks) * (int)blockDim.x + (int)threadIdx.x,
                  CVTB * (int)blockDim.x, n4);
        return;
    }

    int ax = bid & 1;                            // 0 = src (deg), 1 = dst (cnt)
    int ss = (bid >> 1) % nss;
    int c  = bid / (2 * nss);
    const int* __restrict__ arr = ax ? dst : src;

    __shared__ unsigned hp[SS_INTS];             // 4 nodes per int, byte fields
    int lo = ss * SS_NODES;
    int span = min(N - lo, SS_NODES);
    for (int i = threadIdx.x; i < SS_INTS; i += blockDim.x) hp[i] = 0u;
    __syncthreads();

    int beg = c * chunkSz;
    int end = min(E, beg + chunkSz);
    int i = beg + (int)threadIdx.x * 4;
    for (; i + 3 < end; i += blockDim.x * 4) {
        int4 v = *reinterpret_cast<const int4*>(&arr[i]);   // L3-resident re-scan
        unsigned o;
        o = (unsigned)(v.x - lo); if (o < (unsigned)span) atomicAdd(&hp[o >> 2], 1u << (8 * (o & 3)));
        o = (unsigned)(v.y - lo); if (o < (unsigned)span) atomicAdd(&hp[o >> 2], 1u << (8 * (o & 3)));
        o = (unsigned)(v.z - lo); if (o < (unsigned)span) atomicAdd(&hp[o >> 2], 1u << (8 * (o & 3)));
        o = (unsigned)(v.w - lo); if (o < (unsigned)span) atomicAdd(&hp[o >> 2], 1u << (8 * (o & 3)));
    }
    if (i < end) {                               // only if E%4 != 0
        for (int k = i; k < end; ++k) {
            unsigned o = (unsigned)(arr[k] - lo);
            if (o < (unsigned)span) atomicAdd(&hp[o >> 2], 1u << (8 * (o & 3)));
        }
    }
    __syncthreads();

    size_t base = ((size_t)(ax * nss + ss) * nc + c) * SS_INTS;
    for (int j = threadIdx.x; j < SS_INTS; j += blockDim.x) H[base + j] = hp[j];
}

// One thread per (axis, packed-col). 8x unrolled chunk walk: 8 loads in flight.
__global__ void scan_kernel(unsigned* __restrict__ H, float* __restrict__ isd,
                            int* __restrict__ cnt, int* __restrict__ novf,
                            int N, int nss, int nc) {
    int total = nss * SS_INTS;
    int g = blockIdx.x * blockDim.x + threadIdx.x;
    if (g == 0) *novf = 0;                       // folded memset
    if (g >= 2 * total) return;
    int ax = (g >= total) ? 1 : 0;
    int gg = g - ax * total;
    int ss = gg / SS_INTS;
    int i  = gg - ss * SS_INTS;
    int node0 = ss * SS_NODES + 4 * i;

    size_t base = ((size_t)(ax * nss + ss) * nc) * SS_INTS + i;

    if (ax == 0) {
        // src axis: total out-degree -> isd (fused)
        int s0 = 0, s1 = 0, s2 = 0, s3 = 0;
        for (int c = 0; c < nc; c += 8) {
            unsigned w[8];
            #pragma unroll
            for (int u = 0; u < 8; ++u) w[u] = H[base + (size_t)(c + u) * SS_INTS];
            #pragma unroll
            for (int u = 0; u < 8; ++u) {
                s0 += w[u] & 255; s1 += (w[u] >> 8) & 255;
                s2 += (w[u] >> 16) & 255; s3 += w[u] >> 24;
            }
        }
        if (node0 + 0 < N) isd[node0 + 0] = rsqrtf(fmaxf((float)s0, 1.0f));
        if (node0 + 1 < N) isd[node0 + 1] = rsqrtf(fmaxf((float)s1, 1.0f));
        if (node0 + 2 < N) isd[node0 + 2] = rsqrtf(fmaxf((float)s2, 1.0f));
        if (node0 + 3 < N) isd[node0 + 3] = rsqrtf(fmaxf((float)s3, 1.0f));
    } else {
        // dst axis: exclusive per-chunk prefix, in place
        int r0 = 0, r1 = 0, r2 = 0, r3 = 0;
        for (int c = 0; c < nc; c += 8) {
            unsigned w[8];
            #pragma unroll
            for (int u = 0; u < 8; ++u) w[u] = H[base + (size_t)(c + u) * SS_INTS];
            #pragma unroll
            for (int u = 0; u < 8; ++u) {
                unsigned p = (unsigned)min(r0, PCLAMP) | ((unsigned)min(r1, PCLAMP) << 8) |
                             ((unsigned)min(r2, PCLAMP) << 16) | ((unsigned)min(r3, PCLAMP) << 24);
                H[base + (size_t)(c + u) * SS_INTS] = p;
                r0 += w[u] & 255; r1 += (w[u] >> 8) & 255;
                r2 += (w[u] >> 16) & 255; r3 += w[u] >> 24;
            }
        }
        if (node0 + 0 < N) cnt[node0 + 0] = r0;
        if (node0 + 1 < N) cnt[node0 + 1] = r1;
        if (node0 + 2 < N) cnt[node0 + 2] = r2;
        if (node0 + 3 < N) cnt[node0 + 3] = r3;
    }
}

// slice == hist slice now; s = bid % 8 rides the XCD round-robin so each
// slice's 1.6MB bucket window stays in one XCD's L2.
__global__ void scatter_kernel(const int* __restrict__ src, const int* __restrict__ dst,
                               const unsigned* __restrict__ H,  // dst-axis prefixes
                               int* __restrict__ bucket, int2* __restrict__ ovf,
                               int* __restrict__ novf, int E, int N,
                               int nss, int nsc, int chunkSz, int nc) {
    int bid = blockIdx.x;
    int s = bid % nsc;
    int c = bid / nsc;

    __shared__ unsigned lcp[SC_INTS];            // byte-packed running counters
    int lo = s * SC_NODES;
    int span = min(N - lo, SC_NODES);
    size_t base = ((size_t)(nss + s) * nc + c) * SS_INTS;   // ax=1 block, ss=s
    for (int i = threadIdx.x; i < SC_INTS; i += blockDim.x) lcp[i] = H[base + i];
    __syncthreads();

    int beg = c * chunkSz;
    int end = min(E, beg + chunkSz);
    int i = beg + (int)threadIdx.x * 4;
    for (; i + 3 < end; i += blockDim.x * 4) {
        int4 dv = *reinterpret_cast<const int4*>(&dst[i]);  // L3-resident re-scan
        int4 sv = *reinterpret_cast<const int4*>(&src[i]);
        #pragma unroll
        for (int k = 0; k < 4; ++k) {
            int d  = (&dv.x)[k];
            int sx = (&sv.x)[k];
            unsigned o = (unsigned)(d - lo);
            if (o < (unsigned)span) {
                int sh = 8 * (o & 3);
                unsigned old = atomicAdd(&lcp[o >> 2], 1u << sh);  // unique slot
                int slot = (old >> sh) & 255;
                if (slot < CAP) {
                    bucket[d * CAP + slot] = sx;                   // plain store
                } else {
                    int ov = atomicAdd(novf, 1);                   // rare tail
                    ovf[ov] = make_int2(sx, d);
                }
            }
        }
    }
    if (i < end) {                               // only if E%4 != 0
        for (int k = i; k < end; ++k) {
            int d  = dst[k];
            int sx = src[k];
            unsigned o = (unsigned)(d - lo);
            if (o < (unsigned)span) {
                int sh = 8 * (o & 3);
                unsigned old = atomicAdd(&lcp[o >> 2], 1u << sh);
                int slot = (old >> sh) & 255;
                if (slot < CAP) {
                    bucket[d * CAP + slot] = sx;
                } else {
                    int ov = atomicAdd(novf, 1);
                    ovf[ov] = make_int2(sx, d);
                }
            }
        }
    }
}

// Standalone cvt for mode B (x16 unions H: must run after scatter)
__global__ void cvt_kernel(const f32x4* __restrict__ x4,
                           ushort4* __restrict__ x16, int n4) {
    int i = blockIdx.x * blockDim.x + threadIdx.x;
    if (i < n4) cvt_range(x4, x16, i, n4, n4);
}

// 8 nodes per 256-thread block; 32 lanes per node, 4 halves (8B) per lane.
__global__ void gather_kernel(const ushort4* __restrict__ x16,
                              const int* __restrict__ cnt,
                              const int* __restrict__ bucket,
                              const float* __restrict__ isd,
                              f32x4* __restrict__ out4, int N) {
    __shared__ int   sh_idx[NODES_PER_BLOCK * CAP];
    __shared__ float sh_w[NODES_PER_BLOCK * CAP];
    int t = threadIdx.x;
    int node_slot = t >> 5;
    int lane = t & 31;
    int d = blockIdx.x * NODES_PER_BLOCK + node_slot;

    int c = 0;
    if (d < N) {
        c = min(cnt[d], CAP);
        if (lane < c) {
            int s = __builtin_nontemporal_load(&bucket[d * CAP + lane]);  // read-once
            sh_idx[node_slot * CAP + lane] = s;
            sh_w[node_slot * CAP + lane] = isd[s];
        }
    }
    __syncthreads();
    if (d >= N) return;

    f32x4 acc = {0.f, 0.f, 0.f, 0.f};
    #pragma unroll 8
    for (int k = 0; k < c; ++k) {
        int s   = sh_idx[node_slot * CAP + k];   // broadcast LDS read
        float w = sh_w[node_slot * CAP + k];
        ushort4 v = x16[s * 32 + lane];          // 256B coalesced half-row gather
        acc.x += __half2float(__ushort_as_half(v.x)) * w;
        acc.y += __half2float(__ushort_as_half(v.y)) * w;
        acc.z += __half2float(__ushort_as_half(v.z)) * w;
        acc.w += __half2float(__ushort_as_half(v.w)) * w;
    }
    float wd = isd[d];
    acc.x *= wd; acc.y *= wd; acc.z *= wd; acc.w *= wd;
    __builtin_nontemporal_store(acc, &out4[d * 32 + lane]);  // write-once
}

__global__ void overflow_kernel(const float* __restrict__ x,
                                const float* __restrict__ isd,
                                const int2* __restrict__ ovf,
                                const int* __restrict__ novf,
                                float* __restrict__ out) {
    int n = *novf;
    for (int e = blockIdx.x; e < n; e += gridDim.x) {
        int2 sd = ovf[e];
        float coef = isd[sd.x] * isd[sd.y];
        atomicAdd(&out[sd.y * D_FEAT + threadIdx.x],
                  x[sd.x * D_FEAT + threadIdx.x] * coef);
    }
}

// fp32 gather for tier-2
__global__ void gather32_kernel(const float4* __restrict__ x4,
                                const int* __restrict__ cnt,
                                const int* __restrict__ bucket,
                                const float* __restrict__ isd,
                                float4* __restrict__ out4, int N) {
    __shared__ int   sh_idx[NODES_PER_BLOCK * CAP];
    __shared__ float sh_w[NODES_PER_BLOCK * CAP];
    int t = threadIdx.x;
    int node_slot = t >> 5;
    int lane = t & 31;
    int d = blockIdx.x * NODES_PER_BLOCK + node_slot;

    int c = 0;
    if (d < N) {
        c = min(cnt[d], CAP);
        if (lane < c) {
            int s = bucket[d * CAP + lane];
            sh_idx[node_slot * CAP + lane] = s;
            sh_w[node_slot * CAP + lane] = isd[s];
        }
    }
    __syncthreads();
    if (d >= N) return;

    float4 acc = {0.f, 0.f, 0.f, 0.f};
    #pragma unroll 4
    for (int k = 0; k < c; ++k) {
        int s   = sh_idx[node_slot * CAP + k];
        float w = sh_w[node_slot * CAP + k];
        float4 v = x4[s * 32 + lane];
        acc.x += v.x * w; acc.y += v.y * w;
        acc.z += v.z * w; acc.w += v.w * w;
    }
    float wd = isd[d];
    acc.x *= wd; acc.y *= wd; acc.z *= wd; acc.w *= wd;
    out4[d * 32 + lane] = acc;
}

// ---- tier-2 (ws too small for scratch): atomic build ----
#define NSLICES_T2 8
#define BPS 512

__global__ void build_kernel(const int* __restrict__ src, const int* __restrict__ dst,
                             int* __restrict__ deg, int* __restrict__ cnt,
                             int* __restrict__ bucket, int2* __restrict__ ovf,
                             int* __restrict__ novf, int E, int sliceSz) {
    int slice = blockIdx.x & (NSLICES_T2 - 1);
    int chunk = blockIdx.x >> 3;
    int lo = slice * sliceSz;
    int hi = lo + sliceSz;
    int chunkSz = (E + BPS - 1) / BPS;
    int beg = chunk * chunkSz;
    int end = min(E, beg + chunkSz);

    for (int i = beg + (int)threadIdx.x; i < end; i += blockDim.x) {
        int s = src[i];
        int d = dst[i];
        if (d >= lo && d < hi) {
            int slot = atomicAdd(&cnt[d], 1);
            if (slot < CAP) {
                bucket[d * CAP + slot] = s;
            } else {
                int o = atomicAdd(novf, 1);
                ovf[o] = make_int2(s, d);
            }
        }
        if (s >= lo && s < hi) {
            atomicAdd(&deg[s], 1);
        }
    }
}

__global__ void isd_kernel(const int* __restrict__ deg, float* __restrict__ isd, int N) {
    int i = blockIdx.x * blockDim.x + threadIdx.x;
    if (i < N) isd[i] = rsqrtf(fmaxf((float)deg[i], 1.0f));
}

// ---- tier-3 fallback (ws tiny): round-1 atomic scatter ----
__global__ void fb_degree_kernel(const int* __restrict__ src,
                                 float* __restrict__ deg, int E) {
    int i = blockIdx.x * blockDim.x + threadIdx.x;
    if (i < E) atomicAdd(&deg[src[i]], 1.0f);
}
__global__ void fb_inv_sqrt_kernel(float* __restrict__ deg, int N) {
    int i = blockIdx.x * blockDim.x + threadIdx.x;
    if (i < N) deg[i] = rsqrtf(fmaxf(deg[i], 1.0f));
}
__global__ void fb_scatter_kernel(const float* __restrict__ x,
                                  const int* __restrict__ src,
                                  const int* __restrict__ dst,
                                  const float* __restrict__ isd,
                                  float* __restrict__ out, int E) {
    int e = blockIdx.x;
    if (e >= E) return;
    int f = threadIdx.x;
    int s = src[e], d = dst[e];
    float coef = isd[s] * isd[d];
    atomicAdd(&out[(long)d * D_FEAT + f], x[(long)s * D_FEAT + f] * coef);
}

extern "C" void kernel_launch(void* const* d_in, const int* in_sizes, int n_in,
                              void* d_out, int out_size, void* d_ws, size_t ws_size,
                              hipStream_t stream) {
    const float* x   = (const float*)d_in[0];
    const int*   src = (const int*)d_in[1];
    const int*   dst = (const int*)d_in[2];
    float* out = (float*)d_out;

    int N = in_sizes[0] / D_FEAT;   // 100000
    int E = in_sizes[1];            // 1600000

    int nss = (N + SS_NODES - 1) / SS_NODES;    // 8
    int nsc = (N + SC_NODES - 1) / SC_NODES;    // 8

    size_t x16Sz = (size_t)N * D_FEAT * 2;      // 25.6 MB fp16 copy of x
    int n4 = N * (D_FEAT / 4);

    // pick largest chunk count; prefer layout A (separate x16 -> fused cvt)
    int nc = 0, modeA = 0;
    size_t off_cnt = 0, off_isd = 0, off_misc = 0, off_bucket = 0,
           off_H = 0, off_x16 = 0, off_ovf = 0;
    for (int tryNc = 128; tryNc >= 16 && nc == 0; tryNc >>= 1) {
        size_t hSz = (size_t)2 * nss * tryNc * SS_INTS * 4;
        size_t cA  = 0;
        off_cnt    = cA;                         cA += (size_t)N * 4;
        off_isd    = cA;                         cA += (size_t)N * 4;
        off_misc   = cA;                         cA += 64;       // novf
        off_bucket = cA;                         cA += (size_t)N * CAP * 4;
        off_H      = cA;
        // layout A: H and x16 disjoint
        size_t a_x16 = off_H + hSz;
        size_t a_ovf = a_x16 + x16Sz;
        size_t a_need = a_ovf + (size_t)E * 8;
        if (ws_size >= a_need) {
            nc = tryNc; modeA = 1; off_x16 = a_x16; off_ovf = a_ovf;
            break;
        }
        // layout B: x16 unions H (cvt after scatter)
        size_t uSz = hSz > x16Sz ? hSz : x16Sz;
        size_t b_ovf = off_H + uSz;
        size_t b_need = b_ovf + (size_t)E * 8;
        if (ws_size >= b_need) {
            nc = tryNc; modeA = 0; off_x16 = off_H; off_ovf = b_ovf;
            break;
        }
    }

    if (nc > 0) {
        char* ws = (char*)d_ws;
        int*      cnt    = (int*)(ws + off_cnt);
        float*    isd    = (float*)(ws + off_isd);
        int*      novf   = (int*)(ws + off_misc);
        int*      bucket = (int*)(ws + off_bucket);
        unsigned* H      = (unsigned*)(ws + off_H);
        ushort4*  x16    = (ushort4*)(ws + off_x16);
        int2*     ovf    = (int2*)(ws + off_ovf);

        int chunkSz = (((E + nc - 1) / nc) + 3) & ~3;   // 4-aligned
        int histBlocks = 2 * nss * nc;

        if (modeA) {
            hist_kernel<<<histBlocks + CVTB, 256, 0, stream>>>(
                src, dst, H, E, N, nss, chunkSz, nc, histBlocks,
                (const f32x4*)x, x16, n4);
        } else {
            hist_kernel<<<histBlocks, 256, 0, stream>>>(
                src, dst, H, E, N, nss, chunkSz, nc, histBlocks,
                (const f32x4*)x, x16, 0);
        }
        scan_kernel<<<(2 * nss * SS_INTS + 255) / 256, 256, 0, stream>>>(
            H, isd, cnt, novf, N, nss, nc);
        scatter_kernel<<<nsc * nc, 256, 0, stream>>>(
            src, dst, H, bucket, ovf, novf, E, N, nss, nsc, chunkSz, nc);
        if (!modeA) {
            cvt_kernel<<<(n4 + 255) / 256, 256, 0, stream>>>(
                (const f32x4*)x, x16, n4);
        }
        gather_kernel<<<(N + NODES_PER_BLOCK - 1) / NODES_PER_BLOCK, 256, 0, stream>>>(
            x16, cnt, bucket, isd, (f32x4*)out, N);
        overflow_kernel<<<64, D_FEAT, 0, stream>>>(x, isd, ovf, novf, out);
        return;
    }

    // tier-2: atomic build (needs ~26.8MB)
    size_t t2_deg    = 0;
    size_t t2_cnt    = t2_deg + (size_t)N * 4;
    size_t t2_isd    = t2_cnt + (size_t)N * 4;
    size_t t2_novf   = t2_isd + (size_t)N * 4;
    size_t t2_bucket = t2_novf + 16;
    size_t t2_ovf    = t2_bucket + (size_t)N * CAP * 4;
    size_t t2_needed = t2_ovf + (size_t)E * 8;

    if (ws_size >= t2_needed) {
        char* ws = (char*)d_ws;
        int*   deg    = (int*)(ws + t2_deg);
        int*   cnt    = (int*)(ws + t2_cnt);
        float* isd    = (float*)(ws + t2_isd);
        int*   novf   = (int*)(ws + t2_novf);
        int*   bucket = (int*)(ws + t2_bucket);
        int2*  ovf    = (int2*)(ws + t2_ovf);

        hipMemsetAsync(ws, 0, t2_novf + 16, stream);
        int sl = (N + NSLICES_T2 - 1) / NSLICES_T2;
        build_kernel<<<NSLICES_T2 * BPS, 256, 0, stream>>>(src, dst, deg, cnt,
                                                           bucket, ovf, novf, E, sl);
        isd_kernel<<<(N + 255) / 256, 256, 0, stream>>>(deg, isd, N);
        gather32_kernel<<<(N + NODES_PER_BLOCK - 1) / NODES_PER_BLOCK, 256, 0, stream>>>(
            (const float4*)x, cnt, bucket, isd, (float4*)out, N);
        overflow_kernel<<<64, D_FEAT, 0, stream>>>(x, isd, ovf, novf, out);
        return;
    }

    // tier-3 naive
    float* deg = (float*)d_ws;
    hipMemsetAsync(deg, 0, (size_t)N * sizeof(float), stream);
    hipMemsetAsync(out, 0, (size_t)out_size * sizeof(float), stream);
    fb_degree_kernel<<<(E + 255) / 256, 256, 0, stream>>>(src, deg, E);
    fb_inv_sqrt_kernel<<<(N + 255) / 256, 256, 0, stream>>>(deg, N);
    fb_scatter_kernel<<<E, D_FEAT, 0, stream>>>(x, src, dst, deg, out, E);
}

// Round 12
// 241.269 us; speedup vs baseline: 1.6646x; 1.0426x over previous
//
#include <hip/hip_runtime.h>
#include <hip/hip_fp16.h>

// GCNConv: out[v] = isd[v] * sum_{(u->v)} x[u] * isd[u],  isd = rsqrt(max(outdeg,1))
// N=100000, E=1600000, D=128 fp32.
//
// R1 -> R2: bucketed gather killed the 800MB atomic write storm (866 -> 367us).
// R2 -> R3: dst-range slicing for bucket L2 locality (367 -> 343us).
// R3 -> R4 FAILED: scope-relaxed atomics don't escape the coherence point.
// R4 -> R5: atomic-free build (hist -> chunk prefix -> LDS-seeded scatter).
// R5 -> R6: chunk parallelism 16->64: 317us.
// R6 -> R7: byte-packed hist: 304us.
// R7 -> R8: scan ILP + fp16 gather: 253us.
// R8 -> R9 FAILED: bitonic-sorted gather: no FETCH drop, +VALU.
// R9 -> R10: gather unroll8 + nt(bucket,out): gather 82.5us floor. nt on
//            SHARED streams regressed build -- nt only for un-shared lines.
// R10 -> R11: nt-reverts + cvt/hist fusion + novf fold: 251us.
// R11 -> R12 FAILED (402us) but diagnostic: build is latency-bound (23% occ,
//            VALU 3%, HBM 12%) -- 50KB LDS caps residency at 2-3 blocks/CU.
// R12 -> R13 NULL (251.5): 12.5KB slices gave 8 blk/CU but 4x edge traffic --
//            exact cancellation. Lesson: occupancy and scan-redundancy trade
//            through the same LDS-slice knob at 256 threads/block.
// R13 -> R14: break the tradeoff with 1024-THREAD blocks: hist 50KB LDS
//            (nss=2, 51MB edge traffic) x 2 blocks/CU = 100% occupancy;
//            scatter 25KB (nsc=4) same. Fit-loop now prefers mode A
//            (overlapped cvt) at reduced nc over mode B at max nc -- mode B's
//            serial cvt (~14us) was silently selected since R8.

#define D_FEAT 128
#define CAP 32
#define NODES_PER_BLOCK 8   // gather: 256 threads, 32 lanes per node
#define SS_NODES 50000      // hist slice: 50KB byte-packed LDS, 1024 threads
#define SS_INTS  12500
#define SC_NODES 25000      // scatter slice: 25KB LDS, 1024 threads
#define SC_INTS   6250
#define PCLAMP   200
#define CVTB     256        // cvt role blocks (1024 thr) fused into hist launch

typedef float f32x4 __attribute__((ext_vector_type(4)));

__device__ __forceinline__ void cvt_range(const f32x4* __restrict__ x4,
                                          ushort4* __restrict__ x16,
                                          int start, int stride, int n4) {
    for (int i = start; i < n4; i += stride) {
        f32x4 v = __builtin_nontemporal_load(&x4[i]);   // read-once stream
        ushort4 h;
        h.x = __half_as_ushort(__float2half_rn(v.x));
        h.y = __half_as_ushort(__float2half_rn(v.y));
        h.z = __half_as_ushort(__float2half_rn(v.z));
        h.w = __half_as_ushort(__float2half_rn(v.w));
        x16[i] = h;                                     // cached: gather re-reads
    }
}

// ---- atomic-free build pipeline (byte-packed, 1024-thread blocks) ----

// Blocks [0, histBlocks): per-(axis,slice,chunk) LDS histogram, 1024 threads,
// 50KB LDS -> 2 blocks/CU = 100% occupancy AND only 2 slices (51MB edge scan).
// Blocks [histBlocks, +CVTB): grid-stride fp32->fp16 convert (mode A overlap).
__global__ void __launch_bounds__(1024)
hist_kernel(const int* __restrict__ src, const int* __restrict__ dst,
            unsigned* __restrict__ H, int E, int N,
            int nss, int chunkSz, int nc, int histBlocks,
            const f32x4* __restrict__ x4,
            ushort4* __restrict__ x16, int n4) {
    int bid = blockIdx.x;
    if (bid >= histBlocks) {                     // cvt role (mode A only)
        cvt_range(x4, x16, (bid - histBlocks) * (int)blockDim.x + (int)threadIdx.x,
                  CVTB * (int)blockDim.x, n4);
        return;
    }

    int ax = bid & 1;                            // 0 = src (deg), 1 = dst (cnt)
    int ss = (bid >> 1) % nss;
    int c  = bid / (2 * nss);
    const int* __restrict__ arr = ax ? dst : src;

    __shared__ unsigned hp[SS_INTS];             // 4 nodes per int, byte fields
    int lo = ss * SS_NODES;
    int span = min(N - lo, SS_NODES);
    for (int i = threadIdx.x; i < SS_INTS; i += blockDim.x) hp[i] = 0u;
    __syncthreads();

    int beg = c * chunkSz;
    int end = min(E, beg + chunkSz);
    int i = beg + (int)threadIdx.x * 4;
    for (; i + 3 < end; i += blockDim.x * 4) {
        int4 v = *reinterpret_cast<const int4*>(&arr[i]);   // L3-resident
        unsigned o;
        o = (unsigned)(v.x - lo); if (o < (unsigned)span) atomicAdd(&hp[o >> 2], 1u << (8 * (o & 3)));
        o = (unsigned)(v.y - lo); if (o < (unsigned)span) atomicAdd(&hp[o >> 2], 1u << (8 * (o & 3)));
        o = (unsigned)(v.z - lo); if (o < (unsigned)span) atomicAdd(&hp[o >> 2], 1u << (8 * (o & 3)));
        o = (unsigned)(v.w - lo); if (o < (unsigned)span) atomicAdd(&hp[o >> 2], 1u << (8 * (o & 3)));
    }
    if (i < end) {                               // only if E%4 != 0
        for (int k = i; k < end; ++k) {
            unsigned o = (unsigned)(arr[k] - lo);
            if (o < (unsigned)span) atomicAdd(&hp[o >> 2], 1u << (8 * (o & 3)));
        }
    }
    __syncthreads();

    size_t base = ((size_t)(ax * nss + ss) * nc + c) * SS_INTS;
    for (int j = threadIdx.x; j < SS_INTS; j += blockDim.x) H[base + j] = hp[j];
}

// One thread per (axis, packed-col). 8x unrolled chunk walk: 8 loads in flight.
__global__ void scan_kernel(unsigned* __restrict__ H, float* __restrict__ isd,
                            int* __restrict__ cnt, int* __restrict__ novf,
                            int N, int nss, int nc) {
    int total = nss * SS_INTS;
    int g = blockIdx.x * blockDim.x + threadIdx.x;
    if (g == 0) *novf = 0;                       // folded memset
    if (g >= 2 * total) return;
    int ax = (g >= total) ? 1 : 0;
    int gg = g - ax * total;
    int ss = gg / SS_INTS;
    int i  = gg - ss * SS_INTS;
    int node0 = ss * SS_NODES + 4 * i;

    size_t base = ((size_t)(ax * nss + ss) * nc) * SS_INTS + i;

    if (ax == 0) {
        // src axis: total out-degree -> isd (fused)
        int s0 = 0, s1 = 0, s2 = 0, s3 = 0;
        for (int c = 0; c < nc; c += 8) {
            unsigned w[8];
            #pragma unroll
            for (int u = 0; u < 8; ++u) w[u] = H[base + (size_t)(c + u) * SS_INTS];
            #pragma unroll
            for (int u = 0; u < 8; ++u) {
                s0 += w[u] & 255; s1 += (w[u] >> 8) & 255;
                s2 += (w[u] >> 16) & 255; s3 += w[u] >> 24;
            }
        }
        if (node0 + 0 < N) isd[node0 + 0] = rsqrtf(fmaxf((float)s0, 1.0f));
        if (node0 + 1 < N) isd[node0 + 1] = rsqrtf(fmaxf((float)s1, 1.0f));
        if (node0 + 2 < N) isd[node0 + 2] = rsqrtf(fmaxf((float)s2, 1.0f));
        if (node0 + 3 < N) isd[node0 + 3] = rsqrtf(fmaxf((float)s3, 1.0f));
    } else {
        // dst axis: exclusive per-chunk prefix, in place
        int r0 = 0, r1 = 0, r2 = 0, r3 = 0;
        for (int c = 0; c < nc; c += 8) {
            unsigned w[8];
            #pragma unroll
            for (int u = 0; u < 8; ++u) w[u] = H[base + (size_t)(c + u) * SS_INTS];
            #pragma unroll
            for (int u = 0; u < 8; ++u) {
                unsigned p = (unsigned)min(r0, PCLAMP) | ((unsigned)min(r1, PCLAMP) << 8) |
                             ((unsigned)min(r2, PCLAMP) << 16) | ((unsigned)min(r3, PCLAMP) << 24);
                H[base + (size_t)(c + u) * SS_INTS] = p;
                r0 += w[u] & 255; r1 += (w[u] >> 8) & 255;
                r2 += (w[u] >> 16) & 255; r3 += w[u] >> 24;
            }
        }
        if (node0 + 0 < N) cnt[node0 + 0] = r0;
        if (node0 + 1 < N) cnt[node0 + 1] = r1;
        if (node0 + 2 < N) cnt[node0 + 2] = r2;
        if (node0 + 3 < N) cnt[node0 + 3] = r3;
    }
}

// 1024 threads, 25KB LDS -> 2 blocks/CU = 100% occupancy, nsc=4 (51MB scan).
__global__ void __launch_bounds__(1024)
scatter_kernel(const int* __restrict__ src, const int* __restrict__ dst,
               const unsigned* __restrict__ H,  // dst-axis prefixes
               int* __restrict__ bucket, int2* __restrict__ ovf,
               int* __restrict__ novf, int E, int N,
               int nss, int nsc, int chunkSz, int nc) {
    int bid = blockIdx.x;
    int s = bid % nsc;
    int c = bid / nsc;

    __shared__ unsigned lcp[SC_INTS];            // byte-packed running counters
    int lo = s * SC_NODES;
    int span = min(N - lo, SC_NODES);
    int ss = s >> 1;                             // SC = SS/2
    size_t base = ((size_t)(nss + ss) * nc + c) * SS_INTS + (size_t)(s & 1) * SC_INTS;
    for (int i = threadIdx.x; i < SC_INTS; i += blockDim.x) lcp[i] = H[base + i];
    __syncthreads();

    int beg = c * chunkSz;
    int end = min(E, beg + chunkSz);
    int i = beg + (int)threadIdx.x * 4;
    for (; i + 3 < end; i += blockDim.x * 4) {
        int4 dv = *reinterpret_cast<const int4*>(&dst[i]);  // L3-resident
        int4 sv = *reinterpret_cast<const int4*>(&src[i]);
        #pragma unroll
        for (int k = 0; k < 4; ++k) {
            int d  = (&dv.x)[k];
            int sx = (&sv.x)[k];
            unsigned o = (unsigned)(d - lo);
            if (o < (unsigned)span) {
                int sh = 8 * (o & 3);
                unsigned old = atomicAdd(&lcp[o >> 2], 1u << sh);  // unique slot
                int slot = (old >> sh) & 255;
                if (slot < CAP) {
                    bucket[d * CAP + slot] = sx;                   // plain store
                } else {
                    int ov = atomicAdd(novf, 1);                   // rare tail
                    ovf[ov] = make_int2(sx, d);
                }
            }
        }
    }
    if (i < end) {                               // only if E%4 != 0
        for (int k = i; k < end; ++k) {
            int d  = dst[k];
            int sx = src[k];
            unsigned o = (unsigned)(d - lo);
            if (o < (unsigned)span) {
                int sh = 8 * (o & 3);
                unsigned old = atomicAdd(&lcp[o >> 2], 1u << sh);
                int slot = (old >> sh) & 255;
                if (slot < CAP) {
                    bucket[d * CAP + slot] = sx;
                } else {
                    int ov = atomicAdd(novf, 1);
                    ovf[ov] = make_int2(sx, d);
                }
            }
        }
    }
}

// Standalone cvt for mode B (x16 unions H: must run after scatter)
__global__ void cvt_kernel(const f32x4* __restrict__ x4,
                           ushort4* __restrict__ x16, int n4) {
    int i = blockIdx.x * blockDim.x + threadIdx.x;
    if (i < n4) cvt_range(x4, x16, i, n4, n4);
}

// 8 nodes per 256-thread block; 32 lanes per node, 4 halves (8B) per lane.
__global__ void gather_kernel(const ushort4* __restrict__ x16,
                              const int* __restrict__ cnt,
                              const int* __restrict__ bucket,
                              const float* __restrict__ isd,
                              f32x4* __restrict__ out4, int N) {
    __shared__ int   sh_idx[NODES_PER_BLOCK * CAP];
    __shared__ float sh_w[NODES_PER_BLOCK * CAP];
    int t = threadIdx.x;
    int node_slot = t >> 5;
    int lane = t & 31;
    int d = blockIdx.x * NODES_PER_BLOCK + node_slot;

    int c = 0;
    if (d < N) {
        c = min(cnt[d], CAP);
        if (lane < c) {
            int s = __builtin_nontemporal_load(&bucket[d * CAP + lane]);  // read-once
            sh_idx[node_slot * CAP + lane] = s;
            sh_w[node_slot * CAP + lane] = isd[s];
        }
    }
    __syncthreads();
    if (d >= N) return;

    f32x4 acc = {0.f, 0.f, 0.f, 0.f};
    #pragma unroll 8
    for (int k = 0; k < c; ++k) {
        int s   = sh_idx[node_slot * CAP + k];   // broadcast LDS read
        float w = sh_w[node_slot * CAP + k];
        ushort4 v = x16[s * 32 + lane];          // 256B coalesced half-row gather
        acc.x += __half2float(__ushort_as_half(v.x)) * w;
        acc.y += __half2float(__ushort_as_half(v.y)) * w;
        acc.z += __half2float(__ushort_as_half(v.z)) * w;
        acc.w += __half2float(__ushort_as_half(v.w)) * w;
    }
    float wd = isd[d];
    acc.x *= wd; acc.y *= wd; acc.z *= wd; acc.w *= wd;
    __builtin_nontemporal_store(acc, &out4[d * 32 + lane]);  // write-once
}

__global__ void overflow_kernel(const float* __restrict__ x,
                                const float* __restrict__ isd,
                                const int2* __restrict__ ovf,
                                const int* __restrict__ novf,
                                float* __restrict__ out) {
    int n = *novf;
    for (int e = blockIdx.x; e < n; e += gridDim.x) {
        int2 sd = ovf[e];
        float coef = isd[sd.x] * isd[sd.y];
        atomicAdd(&out[sd.y * D_FEAT + threadIdx.x],
                  x[sd.x * D_FEAT + threadIdx.x] * coef);
    }
}

// fp32 gather for tier-2
__global__ void gather32_kernel(const float4* __restrict__ x4,
                                const int* __restrict__ cnt,
                                const int* __restrict__ bucket,
                                const float* __restrict__ isd,
                                float4* __restrict__ out4, int N) {
    __shared__ int   sh_idx[NODES_PER_BLOCK * CAP];
    __shared__ float sh_w[NODES_PER_BLOCK * CAP];
    int t = threadIdx.x;
    int node_slot = t >> 5;
    int lane = t & 31;
    int d = blockIdx.x * NODES_PER_BLOCK + node_slot;

    int c = 0;
    if (d < N) {
        c = min(cnt[d], CAP);
        if (lane < c) {
            int s = bucket[d * CAP + lane];
            sh_idx[node_slot * CAP + lane] = s;
            sh_w[node_slot * CAP + lane] = isd[s];
        }
    }
    __syncthreads();
    if (d >= N) return;

    float4 acc = {0.f, 0.f, 0.f, 0.f};
    #pragma unroll 4
    for (int k = 0; k < c; ++k) {
        int s   = sh_idx[node_slot * CAP + k];
        float w = sh_w[node_slot * CAP + k];
        float4 v = x4[s * 32 + lane];
        acc.x += v.x * w; acc.y += v.y * w;
        acc.z += v.z * w; acc.w += v.w * w;
    }
    float wd = isd[d];
    acc.x *= wd; acc.y *= wd; acc.z *= wd; acc.w *= wd;
    out4[d * 32 + lane] = acc;
}

// ---- tier-2 (ws too small for scratch): atomic build ----
#define NSLICES_T2 8
#define BPS 512

__global__ void build_kernel(const int* __restrict__ src, const int* __restrict__ dst,
                             int* __restrict__ deg, int* __restrict__ cnt,
                             int* __restrict__ bucket, int2* __restrict__ ovf,
                             int* __restrict__ novf, int E, int sliceSz) {
    int slice = blockIdx.x & (NSLICES_T2 - 1);
    int chunk = blockIdx.x >> 3;
    int lo = slice * sliceSz;
    int hi = lo + sliceSz;
    int chunkSz = (E + BPS - 1) / BPS;
    int beg = chunk * chunkSz;
    int end = min(E, beg + chunkSz);

    for (int i = beg + (int)threadIdx.x; i < end; i += blockDim.x) {
        int s = src[i];
        int d = dst[i];
        if (d >= lo && d < hi) {
            int slot = atomicAdd(&cnt[d], 1);
            if (slot < CAP) {
                bucket[d * CAP + slot] = s;
            } else {
                int o = atomicAdd(novf, 1);
                ovf[o] = make_int2(s, d);
            }
        }
        if (s >= lo && s < hi) {
            atomicAdd(&deg[s], 1);
        }
    }
}

__global__ void isd_kernel(const int* __restrict__ deg, float* __restrict__ isd, int N) {
    int i = blockIdx.x * blockDim.x + threadIdx.x;
    if (i < N) isd[i] = rsqrtf(fmaxf((float)deg[i], 1.0f));
}

// ---- tier-3 fallback (ws tiny): round-1 atomic scatter ----
__global__ void fb_degree_kernel(const int* __restrict__ src,
                                 float* __restrict__ deg, int E) {
    int i = blockIdx.x * blockDim.x + threadIdx.x;
    if (i < E) atomicAdd(&deg[src[i]], 1.0f);
}
__global__ void fb_inv_sqrt_kernel(float* __restrict__ deg, int N) {
    int i = blockIdx.x * blockDim.x + threadIdx.x;
    if (i < N) deg[i] = rsqrtf(fmaxf(deg[i], 1.0f));
}
__global__ void fb_scatter_kernel(const float* __restrict__ x,
                                  const int* __restrict__ src,
                                  const int* __restrict__ dst,
                                  const float* __restrict__ isd,
                                  float* __restrict__ out, int E) {
    int e = blockIdx.x;
    if (e >= E) return;
    int f = threadIdx.x;
    int s = src[e], d = dst[e];
    float coef = isd[s] * isd[d];
    atomicAdd(&out[(long)d * D_FEAT + f], x[(long)s * D_FEAT + f] * coef);
}

extern "C" void kernel_launch(void* const* d_in, const int* in_sizes, int n_in,
                              void* d_out, int out_size, void* d_ws, size_t ws_size,
                              hipStream_t stream) {
    const float* x   = (const float*)d_in[0];
    const int*   src = (const int*)d_in[1];
    const int*   dst = (const int*)d_in[2];
    float* out = (float*)d_out;

    int N = in_sizes[0] / D_FEAT;   // 100000
    int E = in_sizes[1];            // 1600000

    int nss = (N + SS_NODES - 1) / SS_NODES;    // 2
    int nsc = (N + SC_NODES - 1) / SC_NODES;    // 4

    size_t x16Sz = (size_t)N * D_FEAT * 2;      // 25.6 MB fp16 copy of x
    int n4 = N * (D_FEAT / 4);

    // fit: mode A (overlapped cvt) strongly preferred -- try ALL nc for A
    // before falling back to mode B (serial cvt).
    int nc = 0, modeA = 0;
    size_t off_cnt = 0, off_isd = 0, off_misc = 0, off_bucket = 0,
           off_H = 0, off_x16 = 0, off_ovf = 0;
    size_t fixedA = (size_t)N * 4 + (size_t)N * 4 + 64 + (size_t)N * CAP * 4;
    for (int tryNc = 128; tryNc >= 16 && nc == 0; tryNc >>= 1) {
        size_t hSz = (size_t)2 * nss * tryNc * SS_INTS * 4;
        size_t a_need = fixedA + hSz + x16Sz + (size_t)E * 8;
        if (ws_size >= a_need) { nc = tryNc; modeA = 1; }
    }
    if (nc == 0) {
        for (int tryNc = 128; tryNc >= 16 && nc == 0; tryNc >>= 1) {
            size_t hSz = (size_t)2 * nss * tryNc * SS_INTS * 4;
            size_t uSz = hSz > x16Sz ? hSz : x16Sz;
            size_t b_need = fixedA + uSz + (size_t)E * 8;
            if (ws_size >= b_need) { nc = tryNc; modeA = 0; }
        }
    }

    if (nc > 0) {
        size_t hSz = (size_t)2 * nss * nc * SS_INTS * 4;
        off_cnt    = 0;
        off_isd    = off_cnt + (size_t)N * 4;
        off_misc   = off_isd + (size_t)N * 4;
        off_bucket = off_misc + 64;
        off_H      = off_bucket + (size_t)N * CAP * 4;
        if (modeA) {
            off_x16 = off_H + hSz;
            off_ovf = off_x16 + x16Sz;
        } else {
            off_x16 = off_H;
            size_t uSz = hSz > x16Sz ? hSz : x16Sz;
            off_ovf = off_H + uSz;
        }

        char* ws = (char*)d_ws;
        int*      cnt    = (int*)(ws + off_cnt);
        float*    isd    = (float*)(ws + off_isd);
        int*      novf   = (int*)(ws + off_misc);
        int*      bucket = (int*)(ws + off_bucket);
        unsigned* H      = (unsigned*)(ws + off_H);
        ushort4*  x16    = (ushort4*)(ws + off_x16);
        int2*     ovf    = (int2*)(ws + off_ovf);

        int chunkSz = (((E + nc - 1) / nc) + 3) & ~3;   // 4-aligned
        int histBlocks = 2 * nss * nc;

        if (modeA) {
            hist_kernel<<<histBlocks + CVTB, 1024, 0, stream>>>(
                src, dst, H, E, N, nss, chunkSz, nc, histBlocks,
                (const f32x4*)x, x16, n4);
        } else {
            hist_kernel<<<histBlocks, 1024, 0, stream>>>(
                src, dst, H, E, N, nss, chunkSz, nc, histBlocks,
                (const f32x4*)x, x16, 0);
        }
        scan_kernel<<<(2 * nss * SS_INTS + 255) / 256, 256, 0, stream>>>(
            H, isd, cnt, novf, N, nss, nc);
        scatter_kernel<<<nsc * nc, 1024, 0, stream>>>(
            src, dst, H, bucket, ovf, novf, E, N, nss, nsc, chunkSz, nc);
        if (!modeA) {
            cvt_kernel<<<(n4 + 255) / 256, 256, 0, stream>>>(
                (const f32x4*)x, x16, n4);
        }
        gather_kernel<<<(N + NODES_PER_BLOCK - 1) / NODES_PER_BLOCK, 256, 0, stream>>>(
            x16, cnt, bucket, isd, (f32x4*)out, N);
        overflow_kernel<<<64, D_FEAT, 0, stream>>>(x, isd, ovf, novf, out);
        return;
    }

    // tier-2: atomic build (needs ~26.8MB)
    size_t t2_deg    = 0;
    size_t t2_cnt    = t2_deg + (size_t)N * 4;
    size_t t2_isd    = t2_cnt + (size_t)N * 4;
    size_t t2_novf   = t2_isd + (size_t)N * 4;
    size_t t2_bucket = t2_novf + 16;
    size_t t2_ovf    = t2_bucket + (size_t)N * CAP * 4;
    size_t t2_needed = t2_ovf + (size_t)E * 8;

    if (ws_size >= t2_needed) {
        char* ws = (char*)d_ws;
        int*   deg    = (int*)(ws + t2_deg);
        int*   cnt    = (int*)(ws + t2_cnt);
        float* isd    = (float*)(ws + t2_isd);
        int*   novf   = (int*)(ws + t2_novf);
        int*   bucket = (int*)(ws + t2_bucket);
        int2*  ovf    = (int2*)(ws + t2_ovf);

        hipMemsetAsync(ws, 0, t2_novf + 16, stream);
        int sl = (N + NSLICES_T2 - 1) / NSLICES_T2;
        build_kernel<<<NSLICES_T2 * BPS, 256, 0, stream>>>(src, dst, deg, cnt,
                                                           bucket, ovf, novf, E, sl);
        isd_kernel<<<(N + 255) / 256, 256, 0, stream>>>(deg, isd, N);
        gather32_kernel<<<(N + NODES_PER_BLOCK - 1) / NODES_PER_BLOCK, 256, 0, stream>>>(
            (const float4*)x, cnt, bucket, isd, (float4*)out, N);
        overflow_kernel<<<64, D_FEAT, 0, stream>>>(x, isd, ovf, novf, out);
        return;
    }

    // tier-3 naive
    float* deg = (float*)d_ws;
    hipMemsetAsync(deg, 0, (size_t)N * sizeof(float), stream);
    hipMemsetAsync(out, 0, (size_t)out_size * sizeof(float), stream);
    fb_degree_kernel<<<(E + 255) / 256, 256, 0, stream>>>(src, deg, E);
    fb_inv_sqrt_kernel<<<(N + 255) / 256, 256, 0, stream>>>(deg, N);
    fb_scatter_kernel<<<E, D_FEAT, 0, stream>>>(x, src, dst, deg, out, E);
}